// Round 2
// baseline (558.656 us; speedup 1.0000x reference)
//
#include <hip/hip_runtime.h>

// out[b,o,h,w] = sum_{i,j in 5x5} K[o][i*5+j] * xpad[b, h+i-2, w+j-2] + bias[o]
// K[o][t!=12] = W[o][t<12 ? t : t-1];  K[o][12] = -sum_c W[o][c]
// (collapse of the reference's 24 shift-subtract channels + 1x1 conv)

#define H_DIM 512
#define W_DIM 512
#define BATCH 16
#define OUTC 32

#define TILE_H 8                   // rows per block (full 512-wide rows)
#define ROWS_STAGE (TILE_H + 4)    // 12 staged rows (2-halo top/bottom)
#define LDS_W 520                  // 516 valid cols (2+512+2), padded for 16B align

__global__ __launch_bounds__(64) void pc_prep(const float* __restrict__ W,
                                              float* __restrict__ K) {
    int o = threadIdx.x;
    if (o < OUTC) {
        float s = 0.f;
        #pragma unroll
        for (int c = 0; c < 24; ++c) s += W[o * 24 + c];
        #pragma unroll
        for (int t = 0; t < 25; ++t) {
            float v = (t == 12) ? -s : W[o * 24 + (t < 12 ? t : t - 1)];
            K[o * 25 + t] = v;
        }
    }
}

// block = 64 x 8 = 512 threads; thread (tx,ty) computes row h0+ty,
// pixels 8*tx .. 8*tx+7, for all 32 output channels.
__global__ __launch_bounds__(512) void pc_conv(const float* __restrict__ x,
                                               const float* __restrict__ K,
                                               const float* __restrict__ bias,
                                               float* __restrict__ out) {
    __shared__ float lds[ROWS_STAGE * LDS_W];   // 24,960 B

    const int b  = blockIdx.y;
    const int h0 = blockIdx.x * TILE_H;
    const int tx = threadIdx.x;                 // 0..63
    const int ty = threadIdx.y;                 // 0..7
    const int tid = ty * 64 + tx;               // 0..511

    const float* xb = x + (size_t)b * H_DIM * W_DIM;

    // ---- stage: interior columns, one column per thread, 12 rows ----
    #pragma unroll
    for (int r = 0; r < ROWS_STAGE; ++r) {
        int gh = h0 - 2 + r;
        float v = 0.f;
        if ((unsigned)gh < (unsigned)H_DIM) v = xb[gh * W_DIM + tid];
        lds[r * LDS_W + 2 + tid] = v;           // lds col (w+2)
    }
    // ---- halo columns w=-2,-1,512,513 are outside the image -> zero ----
    if (tid < ROWS_STAGE * 4) {
        int r  = tid >> 2;                      // 0..11
        int c4 = tid & 3;                       // 0..3
        int c  = (c4 < 2) ? c4 : (512 + c4);    // lds cols 0,1,514,515
        lds[r * LDS_W + c] = 0.f;
    }
    __syncthreads();

    // ---- pull 5 x 12 neighborhood (for 8 output px) into registers ----
    float nb[5][12];
    #pragma unroll
    for (int r = 0; r < 5; ++r) {
        const float* row = &lds[(ty + r) * LDS_W + 8 * tx];  // col 8tx-2 (input)
        float4 a = *(const float4*)(row);
        float4 m = *(const float4*)(row + 4);
        float4 c = *(const float4*)(row + 8);
        nb[r][0] = a.x; nb[r][1]  = a.y; nb[r][2]  = a.z; nb[r][3]  = a.w;
        nb[r][4] = m.x; nb[r][5]  = m.y; nb[r][6]  = m.z; nb[r][7]  = m.w;
        nb[r][8] = c.x; nb[r][9]  = c.y; nb[r][10] = c.z; nb[r][11] = c.w;
    }

    const int h = h0 + ty;
    float* op = out + (size_t)b * OUTC * H_DIM * W_DIM
                    + (size_t)h * W_DIM + 8 * tx;

    #pragma unroll 1
    for (int o = 0; o < OUTC; ++o) {
        const float* kr = K + o * 25;           // wave-uniform -> s_load
        float bb = bias[o];
        float a0 = bb, a1 = bb, a2 = bb, a3 = bb;
        float a4 = bb, a5 = bb, a6 = bb, a7 = bb;
        #pragma unroll
        for (int ki = 0; ki < 5; ++ki) {
            #pragma unroll
            for (int kj = 0; kj < 5; ++kj) {
                float k = kr[ki * 5 + kj];
                a0 += k * nb[ki][kj + 0];
                a1 += k * nb[ki][kj + 1];
                a2 += k * nb[ki][kj + 2];
                a3 += k * nb[ki][kj + 3];
                a4 += k * nb[ki][kj + 4];
                a5 += k * nb[ki][kj + 5];
                a6 += k * nb[ki][kj + 6];
                a7 += k * nb[ki][kj + 7];
            }
        }
        *(float4*)op       = make_float4(a0, a1, a2, a3);
        *(float4*)(op + 4) = make_float4(a4, a5, a6, a7);
        op += H_DIM * W_DIM;
    }
}

extern "C" void kernel_launch(void* const* d_in, const int* in_sizes, int n_in,
                              void* d_out, int out_size, void* d_ws, size_t ws_size,
                              hipStream_t stream) {
    const float* x    = (const float*)d_in[0];
    const float* W    = (const float*)d_in[1];
    const float* bias = (const float*)d_in[2];
    float* out = (float*)d_out;
    float* K   = (float*)d_ws;   // 32*25 floats = 3200 B

    pc_prep<<<1, 64, 0, stream>>>(W, K);

    dim3 grid(H_DIM / TILE_H, BATCH, 1);        // 64 x 16 = 1024 blocks
    dim3 block(64, TILE_H, 1);                  // 512 threads
    pc_conv<<<grid, block, 0, stream>>>(x, K, bias, out);
}